// Round 10
// baseline (522.351 us; speedup 1.0000x reference)
//
#include <hip/hip_runtime.h>
#include <math.h>

#define NN    16384
#define EE    262144
#define ET    (EE + NN)      // edges + self loops
#define NB    8
#define IN_F  768
#define HID1  256
#define H1    4
#define D1    (H1*HID1)      // 1024
#define OUT2  128
#define H2    2
#define D2    (H2*OUT2)      // 256

typedef __attribute__((ext_vector_type(8))) short short8;
typedef __attribute__((ext_vector_type(4))) float f32x4;

__device__ __forceinline__ unsigned short f2bf(float v) {
    unsigned u = __float_as_uint(v);
    u = (u + 0x7FFFu + ((u >> 16) & 1u)) >> 16;
    return (unsigned short)u;
}
__device__ __forceinline__ float bf2f(unsigned short b) {
    return __uint_as_float((unsigned)b << 16);
}

// ---------------- CSR build ----------------

__global__ void hist_kernel(const int* __restrict__ ei, const int* __restrict__ batch,
                            int* __restrict__ deg, int* __restrict__ n_g, int* __restrict__ e_cnt) {
    __shared__ int le[NB], ln[NB];
    int tid = threadIdx.x;
    if (tid < NB) { le[tid] = 0; ln[tid] = 0; }
    __syncthreads();
    int t = blockIdx.x * blockDim.x + tid;
    if (t < EE) {
        int s = ei[t];
        int d = ei[EE + t];
        atomicAdd(&deg[d], 1);
        atomicAdd(&le[batch[s]], 1);
    }
    if (t < NN) {
        atomicAdd(&ln[batch[t]], 1);
    }
    __syncthreads();
    if (tid < NB) {
        if (le[tid]) atomicAdd(&e_cnt[tid], le[tid]);
        if (ln[tid]) atomicAdd(&n_g[tid], ln[tid]);
    }
}

__global__ __launch_bounds__(1024) void scan_kernel(const int* __restrict__ deg, int* __restrict__ row_ptr) {
    __shared__ int sums[1024];
    int t = threadIdx.x;
    int base = t * 16;
    int local[16];
    int acc = 0;
#pragma unroll
    for (int i = 0; i < 16; i++) { local[i] = acc; acc += deg[base + i] + 1; }  // +1 = self loop
    sums[t] = acc;
    __syncthreads();
    for (int off = 1; off < 1024; off <<= 1) {
        int v = (t >= off) ? sums[t - off] : 0;
        __syncthreads();
        sums[t] += v;
        __syncthreads();
    }
    int prev = (t == 0) ? 0 : sums[t - 1];
#pragma unroll
    for (int i = 0; i < 16; i++) row_ptr[base + i] = prev + local[i];
    if (t == 1023) row_ptr[NN] = sums[1023];
}

__global__ void scatter_kernel(const int* __restrict__ ei, const int* __restrict__ row_ptr,
                               int* __restrict__ cursor, int* __restrict__ colidx) {
    int t = blockIdx.x * blockDim.x + threadIdx.x;
    if (t >= ET) return;
    int s, d;
    if (t < EE) { s = ei[t]; d = ei[EE + t]; }
    else        { s = d = t - EE; }
    int pos = row_ptr[d] + atomicAdd(&cursor[d], 1);
    colidx[pos] = s;
}

// ---------------- fp32 -> bf16 splits ----------------

__global__ void split_kernel(const float* __restrict__ in, unsigned short* __restrict__ hi,
                             unsigned short* __restrict__ lo, int n4) {
    int i = blockIdx.x * blockDim.x + threadIdx.x;
    if (i >= n4) return;
    float4 v = ((const float4*)in)[i];
    ushort4 h, l;
    h.x = f2bf(v.x); l.x = f2bf(v.x - bf2f(h.x));
    h.y = f2bf(v.y); l.y = f2bf(v.y - bf2f(h.y));
    h.z = f2bf(v.z); l.z = f2bf(v.z - bf2f(h.z));
    h.w = f2bf(v.w); l.w = f2bf(v.w - bf2f(h.w));
    ((ushort4*)hi)[i] = h;
    ((ushort4*)lo)[i] = l;
}

__global__ void tobf_kernel(const float* __restrict__ in, unsigned short* __restrict__ hi, int n4) {
    int i = blockIdx.x * blockDim.x + threadIdx.x;
    if (i >= n4) return;
    float4 v = ((const float4*)in)[i];
    ushort4 h;
    h.x = f2bf(v.x); h.y = f2bf(v.y); h.z = f2bf(v.z); h.w = f2bf(v.w);
    ((ushort4*)hi)[i] = h;
}

// ---------------- bf16 split MFMA GEMM, bf16 output ----------------
// XOR-swizzled LDS (kills 8-way bank conflict) + XCD-aware block swizzle
// (A-stripe L2-resident). See R8 notes.

__device__ __forceinline__ void ld_lds16(const unsigned short* g, unsigned short* l) {
    __builtin_amdgcn_global_load_lds((__attribute__((address_space(1))) void*)g,
                                     (__attribute__((address_space(3))) void*)l, 16, 0, 0);
}

#define BM 128
#define BN 128
#define BK 32

template <int TERMS>
__global__ __launch_bounds__(256) void gemm_mfma(const unsigned short* __restrict__ Ahi,
                                                 const unsigned short* __restrict__ Alo,
                                                 const unsigned short* __restrict__ Bhi,
                                                 const unsigned short* __restrict__ Blo,
                                                 unsigned short* __restrict__ Cb,
                                                 int M, int N, int K) {
    __shared__ __align__(16) unsigned short sA[2][BM * BK];
    __shared__ __align__(16) unsigned short sB[2][BN * BK];
    int t = threadIdx.x;
    int lane = t & 63, wave = t >> 6;

    int NC = N / BN;
    int b = blockIdx.x;
    int xcd = b & 7;
    int idx = b >> 3;
    int c = idx % NC;
    int rg = idx / NC;
    int bm = (rg * 8 + xcd) * BM;
    int bn = c * BN;

    int wm = (wave & 1) * 64, wn = (wave >> 1) * 64;

    const unsigned short* gbase;
    unsigned short* lbase;
    if      (wave == 0) { gbase = Ahi + (size_t)bm * K; lbase = sA[0]; }
    else if (wave == 1) { gbase = Alo + (size_t)bm * K; lbase = sA[1]; }
    else if (wave == 2) { gbase = Bhi + (size_t)bn * K; lbase = sB[0]; }
    else                { gbase = (TERMS == 3 ? Blo : Bhi) + (size_t)bn * K; lbase = sB[1]; }
    bool do_stage = (wave < 3) || (TERMS == 3);
    int schunk = (lane & 3) ^ ((lane >> 3) & 3);
    const unsigned short* gsrc = gbase + (size_t)(lane >> 2) * K + schunk * 8;

    f32x4 zero = {0.f, 0.f, 0.f, 0.f};
    f32x4 acc[4][4];
#pragma unroll
    for (int i = 0; i < 4; i++)
#pragma unroll
        for (int j = 0; j < 4; j++) acc[i][j] = zero;

    int row16 = lane & 15;
    int kq = ((lane >> 4) ^ ((row16 >> 1) & 3)) * 8;

    for (int k0 = 0; k0 < K; k0 += BK) {
        if (do_stage) {
#pragma unroll
            for (int i = 0; i < 8; i++)
                ld_lds16(gsrc + k0 + (size_t)(i * 16) * K, lbase + i * 16 * BK);
        }
        __syncthreads();

        short8 ah[4], alo[4], bh[4], blo[4];
#pragma unroll
        for (int mt = 0; mt < 4; mt++) {
            int r = (wm + mt * 16 + row16) * BK + kq;
            ah[mt]  = *(const short8*)&sA[0][r];
            alo[mt] = *(const short8*)&sA[1][r];
        }
#pragma unroll
        for (int nt = 0; nt < 4; nt++) {
            int r = (wn + nt * 16 + row16) * BK + kq;
            bh[nt]  = *(const short8*)&sB[0][r];
            if (TERMS == 3) blo[nt] = *(const short8*)&sB[1][r];
        }
#pragma unroll
        for (int mt = 0; mt < 4; mt++)
#pragma unroll
            for (int nt = 0; nt < 4; nt++) {
                acc[mt][nt] = __builtin_amdgcn_mfma_f32_16x16x32_bf16(ah[mt],  bh[nt],  acc[mt][nt], 0, 0, 0);
                acc[mt][nt] = __builtin_amdgcn_mfma_f32_16x16x32_bf16(alo[mt], bh[nt],  acc[mt][nt], 0, 0, 0);
                if (TERMS == 3)
                    acc[mt][nt] = __builtin_amdgcn_mfma_f32_16x16x32_bf16(ah[mt], blo[nt], acc[mt][nt], 0, 0, 0);
            }
        __syncthreads();
    }

    int crow0 = bm + wm + (lane >> 4) * 4;
    int ccol0 = bn + wn + row16;
#pragma unroll
    for (int mt = 0; mt < 4; mt++)
#pragma unroll
        for (int nt = 0; nt < 4; nt++)
#pragma unroll
            for (int reg = 0; reg < 4; reg++)
                Cb[(size_t)(crow0 + mt * 16 + reg) * N + ccol0 + nt * 16] = f2bf(acc[mt][nt][reg]);
}

// ---------------- attention logits ----------------

template <int H, int CH>
__global__ void al_kernel(const unsigned short* __restrict__ h, const float* __restrict__ a_s,
                          const float* __restrict__ a_d, float* __restrict__ als,
                          float* __restrict__ ald) {
    int node = blockIdx.x;
    int wave = threadIdx.x >> 6;
    int lane = threadIdx.x & 63;
    const unsigned short* row = h + (size_t)node * (H * CH) + wave * CH;
    float ss = 0.f, sd = 0.f;
#pragma unroll
    for (int c = lane; c < CH; c += 64) {
        float v = bf2f(row[c]);
        ss += v * a_s[wave * CH + c];
        sd += v * a_d[wave * CH + c];
    }
#pragma unroll
    for (int off = 32; off; off >>= 1) {
        ss += __shfl_down(ss, off);
        sd += __shfl_down(sd, off);
    }
    if (lane == 0) {
        als[node * H + wave] = ss;
        ald[node * H + wave] = sd;
    }
}

__device__ __forceinline__ float leaky(float v) { return v > 0.f ? v : 0.2f * v; }
__device__ __forceinline__ float elu1(float v) { return v > 0.f ? v : (__expf(v) - 1.f); }

// ---------------- softmax stats per (node, head): wave per node ----------------

template <int H>
__global__ __launch_bounds__(256) void stats_kernel(const float* __restrict__ als,
                                                    const float* __restrict__ ald,
                                                    const int* __restrict__ row_ptr,
                                                    const int* __restrict__ colidx,
                                                    float* __restrict__ sm,
                                                    float* __restrict__ sinv) {
    int wave = threadIdx.x >> 6, lane = threadIdx.x & 63;
    int d = blockIdx.x * 4 + wave;
    int start = row_ptr[d], end = row_ptr[d + 1];
    float aldl[H];
#pragma unroll
    for (int hh = 0; hh < H; hh++) aldl[hh] = ald[d * H + hh];

    float mx[H];
#pragma unroll
    for (int hh = 0; hh < H; hh++) mx[hh] = -1e30f;
    for (int e = start + lane; e < end; e += 64) {
        int s = colidx[e];
#pragma unroll
        for (int hh = 0; hh < H; hh++)
            mx[hh] = fmaxf(mx[hh], leaky(als[s * H + hh] + aldl[hh]));
    }
#pragma unroll
    for (int hh = 0; hh < H; hh++)
#pragma unroll
        for (int off = 32; off; off >>= 1)
            mx[hh] = fmaxf(mx[hh], __shfl_xor(mx[hh], off));

    float dn[H];
#pragma unroll
    for (int hh = 0; hh < H; hh++) dn[hh] = 0.f;
    for (int e = start + lane; e < end; e += 64) {
        int s = colidx[e];
#pragma unroll
        for (int hh = 0; hh < H; hh++)
            dn[hh] += __expf(leaky(als[s * H + hh] + aldl[hh]) - mx[hh]);
    }
#pragma unroll
    for (int hh = 0; hh < H; hh++)
#pragma unroll
        for (int off = 32; off; off >>= 1)
            dn[hh] += __shfl_xor(dn[hh], off);

    if (lane == 0) {
#pragma unroll
        for (int hh = 0; hh < H; hh++) {
            sm[d * H + hh]   = mx[hh];
            sinv[d * H + hh] = 1.f / (dn[hh] + 1e-16f);
        }
    }
}

// ---------------- GAT layer 1 aggregation: XCD channel-sliced ----------------
// 8 slices of 128 ch; slice = blockIdx%8 binds slice->XCD (round-robin dispatch)
// so each XCD only touches a 4.2MB slice of the 33.5MB h1bf table -> L2-resident
// (was: every XCD pulled the whole table, FETCH=8x33.5=258MB).
// Wave = (node, slice): lane owns 2 ch (ushort2), stats precomputed, no barriers.

__global__ __launch_bounds__(256) void agg1_kernel(const unsigned short* __restrict__ h,
                                                   const float* __restrict__ als,
                                                   const float* __restrict__ ald,
                                                   const float* __restrict__ sm,
                                                   const float* __restrict__ sinv,
                                                   const int* __restrict__ row_ptr,
                                                   const int* __restrict__ colidx,
                                                   const float* __restrict__ bias,
                                                   unsigned short* __restrict__ out_hi,
                                                   unsigned short* __restrict__ out_lo) {
    int b = blockIdx.x;
    int slice = b & 7;
    int wave = threadIdx.x >> 6, lane = threadIdx.x & 63;
    int d = (b >> 3) * 4 + wave;
    int hd = slice >> 1;                  // head of this slice
    int ch = slice * 128 + lane * 2;      // channel pair in [0, D1)
    int start = row_ptr[d], end = row_ptr[d + 1];

    float aldd = ald[d * H1 + hd];
    float m    = sm[d * H1 + hd];
    float inv  = sinv[d * H1 + hd];

    float ax0 = 0.f, ay0 = 0.f, ax1 = 0.f, ay1 = 0.f;
    float ax2 = 0.f, ay2 = 0.f, ax3 = 0.f, ay3 = 0.f;
    int k = start;
    for (; k + 3 < end; k += 4) {
        int s0 = colidx[k],     s1 = colidx[k + 1];
        int s2 = colidx[k + 2], s3 = colidx[k + 3];
        float w0 = __expf(leaky(als[s0 * H1 + hd] + aldd) - m) * inv;
        float w1 = __expf(leaky(als[s1 * H1 + hd] + aldd) - m) * inv;
        float w2 = __expf(leaky(als[s2 * H1 + hd] + aldd) - m) * inv;
        float w3 = __expf(leaky(als[s3 * H1 + hd] + aldd) - m) * inv;
        ushort2 v0 = *(const ushort2*)(h + (size_t)s0 * D1 + ch);
        ushort2 v1 = *(const ushort2*)(h + (size_t)s1 * D1 + ch);
        ushort2 v2 = *(const ushort2*)(h + (size_t)s2 * D1 + ch);
        ushort2 v3 = *(const ushort2*)(h + (size_t)s3 * D1 + ch);
        ax0 += w0 * bf2f(v0.x); ay0 += w0 * bf2f(v0.y);
        ax1 += w1 * bf2f(v1.x); ay1 += w1 * bf2f(v1.y);
        ax2 += w2 * bf2f(v2.x); ay2 += w2 * bf2f(v2.y);
        ax3 += w3 * bf2f(v3.x); ay3 += w3 * bf2f(v3.y);
    }
    for (; k < end; k++) {
        int s0 = colidx[k];
        float w0 = __expf(leaky(als[s0 * H1 + hd] + aldd) - m) * inv;
        ushort2 v0 = *(const ushort2*)(h + (size_t)s0 * D1 + ch);
        ax0 += w0 * bf2f(v0.x); ay0 += w0 * bf2f(v0.y);
    }
    float ax = (ax0 + ax1) + (ax2 + ax3);
    float ay = (ay0 + ay1) + (ay2 + ay3);

    float2 bv = *(const float2*)(bias + ch);
    float ox = elu1(ax + bv.x);
    float oy = elu1(ay + bv.y);
    ushort2 oh, ol;
    oh.x = f2bf(ox); ol.x = f2bf(ox - bf2f(oh.x));
    oh.y = f2bf(oy); ol.y = f2bf(oy - bf2f(oh.y));
    *(ushort2*)(out_hi + (size_t)d * D1 + ch) = oh;
    *(ushort2*)(out_lo + (size_t)d * D1 + ch) = ol;
}

// ---------------- GAT layer 2 aggregation (no pooled atomics) ----------------

__global__ __launch_bounds__(256) void agg2_kernel(const unsigned short* __restrict__ h,
                                                   const float* __restrict__ als,
                                                   const float* __restrict__ ald,
                                                   const int* __restrict__ row_ptr,
                                                   const int* __restrict__ colidx,
                                                   const float* __restrict__ bias,
                                                   float* __restrict__ out) {
    int d = blockIdx.x;
    int t = threadIdx.x;
    int lane = t & 63, wave = t >> 6;
    int start = row_ptr[d], end = row_ptr[d + 1];

    __shared__ float ald_l[H2];
    __shared__ float wred[4][H2];
    __shared__ float sm[H2], sinv[H2];
    __shared__ int   s_src[128];
    __shared__ float s_w[128 * H2];
    __shared__ float red[256];

    if (t < H2) ald_l[t] = ald[d * H2 + t];
    __syncthreads();

    float mx[H2] = {-1e30f, -1e30f};
    for (int e = start + t; e < end; e += 256) {
        int s = colidx[e];
        const float* as = als + s * H2;
#pragma unroll
        for (int hh = 0; hh < H2; hh++)
            mx[hh] = fmaxf(mx[hh], leaky(as[hh] + ald_l[hh]));
    }
#pragma unroll
    for (int hh = 0; hh < H2; hh++)
#pragma unroll
        for (int off = 32; off; off >>= 1)
            mx[hh] = fmaxf(mx[hh], __shfl_down(mx[hh], off));
    if (lane == 0) {
#pragma unroll
        for (int hh = 0; hh < H2; hh++) wred[wave][hh] = mx[hh];
    }
    __syncthreads();
    if (t < H2) sm[t] = fmaxf(fmaxf(wred[0][t], wred[1][t]), fmaxf(wred[2][t], wred[3][t]));
    __syncthreads();

    float dn[H2] = {0.f, 0.f};
    for (int e = start + t; e < end; e += 256) {
        int s = colidx[e];
        const float* as = als + s * H2;
#pragma unroll
        for (int hh = 0; hh < H2; hh++)
            dn[hh] += __expf(leaky(as[hh] + ald_l[hh]) - sm[hh]);
    }
#pragma unroll
    for (int hh = 0; hh < H2; hh++)
#pragma unroll
        for (int off = 32; off; off >>= 1)
            dn[hh] += __shfl_down(dn[hh], off);
    if (lane == 0) {
#pragma unroll
        for (int hh = 0; hh < H2; hh++) wred[wave][hh] = dn[hh];
    }
    __syncthreads();
    if (t < H2) sinv[t] = 1.f / (wred[0][t] + wred[1][t] + wred[2][t] + wred[3][t] + 1e-16f);
    __syncthreads();

    // pass 3: k-loop unrolled x4 with independent accumulators
    float a0 = 0.f, a1 = 0.f, a2 = 0.f, a3 = 0.f;
    int myh = t >> 7;
    for (int base = start; base < end; base += 128) {
        int ne = min(128, end - base);
        if (t < ne * 2) {
            int ei = t >> 1, hh = t & 1;
            int s = colidx[base + ei];
            if (hh == 0) s_src[ei] = s;
            float v = leaky(als[s * H2 + hh] + ald_l[hh]);
            s_w[(ei << 1) + hh] = __expf(v - sm[hh]) * sinv[hh];
        }
        __syncthreads();
        int k = 0;
        for (; k + 3 < ne; k += 4) {
            int s0 = s_src[k],     s1 = s_src[k + 1];
            int s2 = s_src[k + 2], s3 = s_src[k + 3];
            float w0 = s_w[(k << 1) + myh],       w1 = s_w[((k + 1) << 1) + myh];
            float w2 = s_w[((k + 2) << 1) + myh], w3 = s_w[((k + 3) << 1) + myh];
            unsigned short v0 = h[(size_t)s0 * D2 + t];
            unsigned short v1 = h[(size_t)s1 * D2 + t];
            unsigned short v2 = h[(size_t)s2 * D2 + t];
            unsigned short v3 = h[(size_t)s3 * D2 + t];
            a0 += w0 * bf2f(v0); a1 += w1 * bf2f(v1);
            a2 += w2 * bf2f(v2); a3 += w3 * bf2f(v3);
        }
        for (; k < ne; k++) {
            a0 += s_w[(k << 1) + myh] * bf2f(h[(size_t)s_src[k] * D2 + t]);
        }
        __syncthreads();
    }
    red[t] = (a0 + a1) + (a2 + a3);
    __syncthreads();
    if (t < 128) {
        float v = (red[t] + red[t + 128]) * 0.5f + bias[t];
        out[(size_t)d * OUT2 + t] = elu1(v);
    }
}

// ---------------- pooling: per-graph sum of h2out (batch is SORTED) ----------------

__global__ __launch_bounds__(256) void pool_kernel(const float* __restrict__ h2,
                                                   const int* __restrict__ batch,
                                                   float* __restrict__ pooled) {
    int c = threadIdx.x & 127;
    int half = threadIdx.x >> 7;
    int n0 = blockIdx.x * 256 + half;
    int nend = blockIdx.x * 256 + 256;
    float acc = 0.f;
    int curg = batch[n0];
    for (int n = n0; n < nend; n += 2) {
        int g = batch[n];
        if (g != curg) {
            atomicAdd(&pooled[curg * OUT2 + c], acc);
            acc = 0.f; curg = g;
        }
        acc += h2[(size_t)n * OUT2 + c];
    }
    atomicAdd(&pooled[curg * OUT2 + c], acc);
}

// ---------------- per-graph head: proj + LN + risk MLP ----------------

__global__ __launch_bounds__(256) void final_kernel(const float* __restrict__ pooled_sum,
                                                    const int* __restrict__ n_g_i,
                                                    const int* __restrict__ e_cnt,
                                                    const float* __restrict__ projW,
                                                    const float* __restrict__ projb,
                                                    const float* __restrict__ lng,
                                                    const float* __restrict__ lnb,
                                                    const float* __restrict__ rhW1,
                                                    const float* __restrict__ rhb1,
                                                    const float* __restrict__ rhW2,
                                                    const float* __restrict__ rhb2,
                                                    float* __restrict__ out_se,
                                                    float* __restrict__ out_risk) {
    int b = blockIdx.x;
    int t = threadIdx.x;
    __shared__ float pooled[OUT2];
    __shared__ float pe[768];
    __shared__ float red[256];
    __shared__ float hid[32];
    __shared__ float stat_mu, stat_inv;

    float ng = (float)n_g_i[b];
    if (t < OUT2) pooled[t] = pooled_sum[b * OUT2 + t] / fmaxf(ng, 1.0f);
    __syncthreads();

    for (int j = t; j < 768; j += 256) {
        const float* wr = projW + (size_t)j * OUT2;
        float s = projb[j];
        for (int c = 0; c < OUT2; c++) s += pooled[c] * wr[c];
        pe[j] = s;
    }
    __syncthreads();

    float ls = 0.f, lq = 0.f;
    for (int j = t; j < 768; j += 256) { float v = pe[j]; ls += v; lq += v * v; }
    red[t] = ls;
    __syncthreads();
    for (int off = 128; off; off >>= 1) { if (t < off) red[t] += red[t + off]; __syncthreads(); }
    float tot = red[0];
    __syncthreads();
    red[t] = lq;
    __syncthreads();
    for (int off = 128; off; off >>= 1) { if (t < off) red[t] += red[t + off]; __syncthreads(); }
    float totq = red[0];
    if (t == 0) {
        float mu = tot / 768.f;
        float var = totq / 768.f - mu * mu;
        stat_mu = mu;
        stat_inv = 1.f / sqrtf(var + 1e-5f);
    }
    __syncthreads();
    float mu = stat_mu, inv = stat_inv;
    for (int j = t; j < 768; j += 256)
        out_se[(size_t)b * 768 + j] = (pe[j] - mu) * inv * lng[j] + lnb[j];

    float s0 = (float)e_cnt[b] / (ng + 1e-6f);
    float s1 = logf(ng + 1.0f);
    if (t < 32) {
        const float* wr = rhW1 + t * (OUT2 + 2);
        float s = rhb1[t];
        for (int c = 0; c < OUT2; c++) s += pooled[c] * wr[c];
        s += s0 * wr[OUT2] + s1 * wr[OUT2 + 1];
        hid[t] = fmaxf(s, 0.f);
    }
    __syncthreads();
    if (t == 0) {
        float s = rhb2[0];
        for (int k = 0; k < 32; k++) s += hid[k] * rhW2[k];
        out_risk[b] = 1.f / (1.f + __expf(-s));
    }
}

// ---------------- launch ----------------

extern "C" void kernel_launch(void* const* d_in, const int* in_sizes, int n_in,
                              void* d_out, int out_size, void* d_ws, size_t ws_size,
                              hipStream_t stream) {
    const float* x     = (const float*)d_in[0];
    const int*   ei    = (const int*)  d_in[1];
    const int*   batch = (const int*)  d_in[2];
    const float* W1    = (const float*)d_in[3];
    const float* a_s1  = (const float*)d_in[4];
    const float* a_d1  = (const float*)d_in[5];
    const float* b1    = (const float*)d_in[6];
    const float* W2    = (const float*)d_in[7];
    const float* a_s2  = (const float*)d_in[8];
    const float* a_d2  = (const float*)d_in[9];
    const float* b2    = (const float*)d_in[10];
    const float* projW = (const float*)d_in[11];
    const float* projb = (const float*)d_in[12];
    const float* lng   = (const float*)d_in[13];
    const float* lnb   = (const float*)d_in[14];
    const float* rhW1  = (const float*)d_in[15];
    const float* rhb1  = (const float*)d_in[16];
    const float* rhW2  = (const float*)d_in[17];
    const float* rhb2  = (const float*)d_in[18];

    char* ws = (char*)d_ws;
    size_t off = 0;
    auto alloc = [&](size_t bytes) -> void* {
        void* p = ws + off;
        off += (bytes + 255) & ~(size_t)255;
        return p;
    };

    unsigned short* regionA = (unsigned short*)alloc((size_t)2 * NN * D1 * 2);
    unsigned short* x_hi = regionA;
    unsigned short* x_lo = regionA + (size_t)NN * IN_F;
    unsigned short* h1hi = regionA;
    unsigned short* h1lo = regionA + (size_t)NN * D1;

    unsigned short* h1bf = (unsigned short*)alloc((size_t)NN * D1 * 2);
    unsigned short* h2bf = (unsigned short*)alloc((size_t)NN * D2 * 2);
    unsigned short* W1hi = (unsigned short*)alloc((size_t)D1 * IN_F * 2);
    unsigned short* W2hi = (unsigned short*)alloc((size_t)D2 * D1 * 2);
    unsigned short* W2lo = (unsigned short*)alloc((size_t)D2 * D1 * 2);
    float* als1   = (float*)alloc((size_t)NN * H1 * 4);
    float* ald1   = (float*)alloc((size_t)NN * H1 * 4);
    float* sm1    = (float*)alloc((size_t)NN * H1 * 4);
    float* sinv1  = (float*)alloc((size_t)NN * H1 * 4);
    float* als2   = (float*)alloc((size_t)NN * H2 * 4);
    float* ald2   = (float*)alloc((size_t)NN * H2 * 4);
    int*   row_ptr= (int*)  alloc((size_t)(NN + 1) * 4);
    int*   colidx = (int*)  alloc((size_t)ET * 4);
    size_t zoff = off;
    int*   deg    = (int*)  alloc((size_t)NN * 4);
    int*   cursor = (int*)  alloc((size_t)NN * 4);
    int*   n_g    = (int*)  alloc((size_t)NB * 4);
    int*   e_cnt  = (int*)  alloc((size_t)NB * 4);
    float* pooled = (float*)alloc((size_t)NB * OUT2 * 4);
    size_t zbytes = off - zoff;

    float* out_se   = (float*)d_out;
    float* h2out    = out_se + NB * 768;
    float* out_risk = h2out + (size_t)NN * OUT2;

    hipMemsetAsync(ws + zoff, 0, zbytes, stream);

    hist_kernel<<<(EE + 255) / 256, 256, 0, stream>>>(ei, batch, deg, n_g, e_cnt);
    scan_kernel<<<1, 1024, 0, stream>>>(deg, row_ptr);
    scatter_kernel<<<(ET + 255) / 256, 256, 0, stream>>>(ei, row_ptr, cursor, colidx);

    split_kernel<<<((NN * IN_F / 4) + 255) / 256, 256, 0, stream>>>(x, x_hi, x_lo, NN * IN_F / 4);
    tobf_kernel<<<((D1 * IN_F / 4) + 255) / 256, 256, 0, stream>>>(W1, W1hi, D1 * IN_F / 4);
    split_kernel<<<((D2 * D1 / 4) + 255) / 256, 256, 0, stream>>>(W2, W2hi, W2lo, D2 * D1 / 4);

    gemm_mfma<2><<<(NN / BM) * (D1 / BN), 256, 0, stream>>>(x_hi, x_lo, W1hi, W1hi, h1bf, NN, D1, IN_F);
    al_kernel<H1, HID1><<<NN, H1 * 64, 0, stream>>>(h1bf, a_s1, a_d1, als1, ald1);
    stats_kernel<H1><<<NN / 4, 256, 0, stream>>>(als1, ald1, row_ptr, colidx, sm1, sinv1);
    agg1_kernel<<<(NN / 4) * 8, 256, 0, stream>>>(h1bf, als1, ald1, sm1, sinv1,
                                                  row_ptr, colidx, b1, h1hi, h1lo);

    gemm_mfma<3><<<(NN / BM) * (D2 / BN), 256, 0, stream>>>(h1hi, h1lo, W2hi, W2lo, h2bf, NN, D2, D1);
    al_kernel<H2, OUT2><<<NN, H2 * 64, 0, stream>>>(h2bf, a_s2, a_d2, als2, ald2);
    agg2_kernel<<<NN, 256, 0, stream>>>(h2bf, als2, ald2, row_ptr, colidx, b2, h2out);

    pool_kernel<<<NN / 256, 256, 0, stream>>>(h2out, batch, pooled);

    final_kernel<<<NB, 256, 0, stream>>>(pooled, n_g, e_cnt, projW, projb, lng, lnb,
                                         rhW1, rhb1, rhW2, rhb2, out_se, out_risk);
}

// Round 11
// 515.421 us; speedup vs baseline: 1.0134x; 1.0134x over previous
//
#include <hip/hip_runtime.h>
#include <math.h>

#define NN    16384
#define EE    262144
#define ET    (EE + NN)      // edges + self loops
#define NB    8
#define IN_F  768
#define HID1  256
#define H1    4
#define D1    (H1*HID1)      // 1024
#define OUT2  128
#define H2    2
#define D2    (H2*OUT2)      // 256

typedef __attribute__((ext_vector_type(8))) short short8;
typedef __attribute__((ext_vector_type(4))) float f32x4;

__device__ __forceinline__ unsigned short f2bf(float v) {
    unsigned u = __float_as_uint(v);
    u = (u + 0x7FFFu + ((u >> 16) & 1u)) >> 16;
    return (unsigned short)u;
}
__device__ __forceinline__ float bf2f(unsigned short b) {
    return __uint_as_float((unsigned)b << 16);
}

// ---------------- CSR build ----------------

__global__ void hist_kernel(const int* __restrict__ ei, const int* __restrict__ batch,
                            int* __restrict__ deg, int* __restrict__ n_g, int* __restrict__ e_cnt) {
    __shared__ int le[NB], ln[NB];
    int tid = threadIdx.x;
    if (tid < NB) { le[tid] = 0; ln[tid] = 0; }
    __syncthreads();
    int t = blockIdx.x * blockDim.x + tid;
    if (t < EE) {
        int s = ei[t];
        int d = ei[EE + t];
        atomicAdd(&deg[d], 1);
        atomicAdd(&le[batch[s]], 1);
    }
    if (t < NN) {
        atomicAdd(&ln[batch[t]], 1);
    }
    __syncthreads();
    if (tid < NB) {
        if (le[tid]) atomicAdd(&e_cnt[tid], le[tid]);
        if (ln[tid]) atomicAdd(&n_g[tid], ln[tid]);
    }
}

__global__ __launch_bounds__(1024) void scan_kernel(const int* __restrict__ deg, int* __restrict__ row_ptr) {
    __shared__ int sums[1024];
    int t = threadIdx.x;
    int base = t * 16;
    int local[16];
    int acc = 0;
#pragma unroll
    for (int i = 0; i < 16; i++) { local[i] = acc; acc += deg[base + i] + 1; }  // +1 = self loop
    sums[t] = acc;
    __syncthreads();
    for (int off = 1; off < 1024; off <<= 1) {
        int v = (t >= off) ? sums[t - off] : 0;
        __syncthreads();
        sums[t] += v;
        __syncthreads();
    }
    int prev = (t == 0) ? 0 : sums[t - 1];
#pragma unroll
    for (int i = 0; i < 16; i++) row_ptr[base + i] = prev + local[i];
    if (t == 1023) row_ptr[NN] = sums[1023];
}

__global__ void scatter_kernel(const int* __restrict__ ei, const int* __restrict__ row_ptr,
                               int* __restrict__ cursor, int* __restrict__ colidx) {
    int t = blockIdx.x * blockDim.x + threadIdx.x;
    if (t >= ET) return;
    int s, d;
    if (t < EE) { s = ei[t]; d = ei[EE + t]; }
    else        { s = d = t - EE; }
    int pos = row_ptr[d] + atomicAdd(&cursor[d], 1);
    colidx[pos] = s;
}

// ---------------- fp32 -> bf16 splits ----------------

__global__ void split_kernel(const float* __restrict__ in, unsigned short* __restrict__ hi,
                             unsigned short* __restrict__ lo, int n4) {
    int i = blockIdx.x * blockDim.x + threadIdx.x;
    if (i >= n4) return;
    float4 v = ((const float4*)in)[i];
    ushort4 h, l;
    h.x = f2bf(v.x); l.x = f2bf(v.x - bf2f(h.x));
    h.y = f2bf(v.y); l.y = f2bf(v.y - bf2f(h.y));
    h.z = f2bf(v.z); l.z = f2bf(v.z - bf2f(h.z));
    h.w = f2bf(v.w); l.w = f2bf(v.w - bf2f(h.w));
    ((ushort4*)hi)[i] = h;
    ((ushort4*)lo)[i] = l;
}

__global__ void tobf_kernel(const float* __restrict__ in, unsigned short* __restrict__ hi, int n4) {
    int i = blockIdx.x * blockDim.x + threadIdx.x;
    if (i >= n4) return;
    float4 v = ((const float4*)in)[i];
    ushort4 h;
    h.x = f2bf(v.x); h.y = f2bf(v.y); h.z = f2bf(v.z); h.w = f2bf(v.w);
    ((ushort4*)hi)[i] = h;
}

// ---------------- bf16 split MFMA GEMM, bf16 output ----------------
// XOR-swizzled LDS (kills 8-way bank conflict) + XCD-aware block swizzle
// (A-stripe L2-resident). See R8 notes.

__device__ __forceinline__ void ld_lds16(const unsigned short* g, unsigned short* l) {
    __builtin_amdgcn_global_load_lds((__attribute__((address_space(1))) void*)g,
                                     (__attribute__((address_space(3))) void*)l, 16, 0, 0);
}

#define BM 128
#define BN 128
#define BK 32

template <int TERMS>
__global__ __launch_bounds__(256) void gemm_mfma(const unsigned short* __restrict__ Ahi,
                                                 const unsigned short* __restrict__ Alo,
                                                 const unsigned short* __restrict__ Bhi,
                                                 const unsigned short* __restrict__ Blo,
                                                 unsigned short* __restrict__ Cb,
                                                 int M, int N, int K) {
    __shared__ __align__(16) unsigned short sA[2][BM * BK];
    __shared__ __align__(16) unsigned short sB[2][BN * BK];
    int t = threadIdx.x;
    int lane = t & 63, wave = t >> 6;

    int NC = N / BN;
    int b = blockIdx.x;
    int xcd = b & 7;
    int idx = b >> 3;
    int c = idx % NC;
    int rg = idx / NC;
    int bm = (rg * 8 + xcd) * BM;
    int bn = c * BN;

    int wm = (wave & 1) * 64, wn = (wave >> 1) * 64;

    const unsigned short* gbase;
    unsigned short* lbase;
    if      (wave == 0) { gbase = Ahi + (size_t)bm * K; lbase = sA[0]; }
    else if (wave == 1) { gbase = Alo + (size_t)bm * K; lbase = sA[1]; }
    else if (wave == 2) { gbase = Bhi + (size_t)bn * K; lbase = sB[0]; }
    else                { gbase = (TERMS == 3 ? Blo : Bhi) + (size_t)bn * K; lbase = sB[1]; }
    bool do_stage = (wave < 3) || (TERMS == 3);
    int schunk = (lane & 3) ^ ((lane >> 3) & 3);
    const unsigned short* gsrc = gbase + (size_t)(lane >> 2) * K + schunk * 8;

    f32x4 zero = {0.f, 0.f, 0.f, 0.f};
    f32x4 acc[4][4];
#pragma unroll
    for (int i = 0; i < 4; i++)
#pragma unroll
        for (int j = 0; j < 4; j++) acc[i][j] = zero;

    int row16 = lane & 15;
    int kq = ((lane >> 4) ^ ((row16 >> 1) & 3)) * 8;

    for (int k0 = 0; k0 < K; k0 += BK) {
        if (do_stage) {
#pragma unroll
            for (int i = 0; i < 8; i++)
                ld_lds16(gsrc + k0 + (size_t)(i * 16) * K, lbase + i * 16 * BK);
        }
        __syncthreads();

        short8 ah[4], alo[4], bh[4], blo[4];
#pragma unroll
        for (int mt = 0; mt < 4; mt++) {
            int r = (wm + mt * 16 + row16) * BK + kq;
            ah[mt]  = *(const short8*)&sA[0][r];
            alo[mt] = *(const short8*)&sA[1][r];
        }
#pragma unroll
        for (int nt = 0; nt < 4; nt++) {
            int r = (wn + nt * 16 + row16) * BK + kq;
            bh[nt]  = *(const short8*)&sB[0][r];
            if (TERMS == 3) blo[nt] = *(const short8*)&sB[1][r];
        }
#pragma unroll
        for (int mt = 0; mt < 4; mt++)
#pragma unroll
            for (int nt = 0; nt < 4; nt++) {
                acc[mt][nt] = __builtin_amdgcn_mfma_f32_16x16x32_bf16(ah[mt],  bh[nt],  acc[mt][nt], 0, 0, 0);
                acc[mt][nt] = __builtin_amdgcn_mfma_f32_16x16x32_bf16(alo[mt], bh[nt],  acc[mt][nt], 0, 0, 0);
                if (TERMS == 3)
                    acc[mt][nt] = __builtin_amdgcn_mfma_f32_16x16x32_bf16(ah[mt], blo[nt], acc[mt][nt], 0, 0, 0);
            }
        __syncthreads();
    }

    int crow0 = bm + wm + (lane >> 4) * 4;
    int ccol0 = bn + wn + row16;
#pragma unroll
    for (int mt = 0; mt < 4; mt++)
#pragma unroll
        for (int nt = 0; nt < 4; nt++)
#pragma unroll
            for (int reg = 0; reg < 4; reg++)
                Cb[(size_t)(crow0 + mt * 16 + reg) * N + ccol0 + nt * 16] = f2bf(acc[mt][nt][reg]);
}

// ---------------- attention logits ----------------

template <int H, int CH>
__global__ void al_kernel(const unsigned short* __restrict__ h, const float* __restrict__ a_s,
                          const float* __restrict__ a_d, float* __restrict__ als,
                          float* __restrict__ ald) {
    int node = blockIdx.x;
    int wave = threadIdx.x >> 6;
    int lane = threadIdx.x & 63;
    const unsigned short* row = h + (size_t)node * (H * CH) + wave * CH;
    float ss = 0.f, sd = 0.f;
#pragma unroll
    for (int c = lane; c < CH; c += 64) {
        float v = bf2f(row[c]);
        ss += v * a_s[wave * CH + c];
        sd += v * a_d[wave * CH + c];
    }
#pragma unroll
    for (int off = 32; off; off >>= 1) {
        ss += __shfl_down(ss, off);
        sd += __shfl_down(sd, off);
    }
    if (lane == 0) {
        als[node * H + wave] = ss;
        ald[node * H + wave] = sd;
    }
}

__device__ __forceinline__ float leaky(float v) { return v > 0.f ? v : 0.2f * v; }
__device__ __forceinline__ float elu1(float v) { return v > 0.f ? v : (__expf(v) - 1.f); }

// ---------------- per-edge softmax weights (layer 1): wave per node ----------------
// Computes the full softmax weight for every CSR edge once and stores it
// head-major (wt[hd*ET + e]) so agg1's 8 slice-waves per node just stream it
// (R10's agg1 recomputed exp 8x per edge -> VALUBusy 92%).

__global__ __launch_bounds__(256) void wstats1_kernel(const float* __restrict__ als,
                                                      const float* __restrict__ ald,
                                                      const int* __restrict__ row_ptr,
                                                      const int* __restrict__ colidx,
                                                      float* __restrict__ wt) {
    int wave = threadIdx.x >> 6, lane = threadIdx.x & 63;
    int d = blockIdx.x * 4 + wave;
    int start = row_ptr[d], end = row_ptr[d + 1];
    float aldl[H1];
#pragma unroll
    for (int hh = 0; hh < H1; hh++) aldl[hh] = ald[d * H1 + hh];

    float mx[H1];
#pragma unroll
    for (int hh = 0; hh < H1; hh++) mx[hh] = -1e30f;
    for (int e = start + lane; e < end; e += 64) {
        int s = colidx[e];
        float4 as = *(const float4*)(als + s * H1);
        mx[0] = fmaxf(mx[0], leaky(as.x + aldl[0]));
        mx[1] = fmaxf(mx[1], leaky(as.y + aldl[1]));
        mx[2] = fmaxf(mx[2], leaky(as.z + aldl[2]));
        mx[3] = fmaxf(mx[3], leaky(as.w + aldl[3]));
    }
#pragma unroll
    for (int hh = 0; hh < H1; hh++)
#pragma unroll
        for (int off = 32; off; off >>= 1)
            mx[hh] = fmaxf(mx[hh], __shfl_xor(mx[hh], off));

    float dn[H1] = {0.f, 0.f, 0.f, 0.f};
    for (int e = start + lane; e < end; e += 64) {
        int s = colidx[e];
        float4 as = *(const float4*)(als + s * H1);
        dn[0] += __expf(leaky(as.x + aldl[0]) - mx[0]);
        dn[1] += __expf(leaky(as.y + aldl[1]) - mx[1]);
        dn[2] += __expf(leaky(as.z + aldl[2]) - mx[2]);
        dn[3] += __expf(leaky(as.w + aldl[3]) - mx[3]);
    }
#pragma unroll
    for (int hh = 0; hh < H1; hh++)
#pragma unroll
        for (int off = 32; off; off >>= 1)
            dn[hh] += __shfl_xor(dn[hh], off);
    float inv[H1];
#pragma unroll
    for (int hh = 0; hh < H1; hh++) inv[hh] = 1.f / (dn[hh] + 1e-16f);

    for (int e = start + lane; e < end; e += 64) {
        int s = colidx[e];
        float4 as = *(const float4*)(als + s * H1);
        wt[0 * (size_t)ET + e] = __expf(leaky(as.x + aldl[0]) - mx[0]) * inv[0];
        wt[1 * (size_t)ET + e] = __expf(leaky(as.y + aldl[1]) - mx[1]) * inv[1];
        wt[2 * (size_t)ET + e] = __expf(leaky(as.z + aldl[2]) - mx[2]) * inv[2];
        wt[3 * (size_t)ET + e] = __expf(leaky(as.w + aldl[3]) - mx[3]) * inv[3];
    }
}

// ---------------- GAT layer 1 aggregation: XCD channel-sliced, precomputed w ----------------
// 8 slices of 128 ch; slice = blockIdx%8 binds slice->XCD so each XCD touches a
// 4.2MB slice of h1bf (L2-resident; FETCH 258->91MB, R10). Weights precomputed
// (wstats1) so the inner loop is pure stream+gather+fma.

__global__ __launch_bounds__(256) void agg1_kernel(const unsigned short* __restrict__ h,
                                                   const float* __restrict__ wt,
                                                   const int* __restrict__ row_ptr,
                                                   const int* __restrict__ colidx,
                                                   const float* __restrict__ bias,
                                                   unsigned short* __restrict__ out_hi,
                                                   unsigned short* __restrict__ out_lo) {
    int b = blockIdx.x;
    int slice = b & 7;
    int wave = threadIdx.x >> 6, lane = threadIdx.x & 63;
    int d = (b >> 3) * 4 + wave;
    int hd = slice >> 1;
    int ch = slice * 128 + lane * 2;
    int start = row_ptr[d], end = row_ptr[d + 1];
    const float* w = wt + (size_t)hd * ET;

    float ax0 = 0.f, ay0 = 0.f, ax1 = 0.f, ay1 = 0.f;
    float ax2 = 0.f, ay2 = 0.f, ax3 = 0.f, ay3 = 0.f;
    int k = start;
    for (; k + 3 < end; k += 4) {
        int s0 = colidx[k],     s1 = colidx[k + 1];
        int s2 = colidx[k + 2], s3 = colidx[k + 3];
        float w0 = w[k], w1 = w[k + 1], w2 = w[k + 2], w3 = w[k + 3];
        ushort2 v0 = *(const ushort2*)(h + (size_t)s0 * D1 + ch);
        ushort2 v1 = *(const ushort2*)(h + (size_t)s1 * D1 + ch);
        ushort2 v2 = *(const ushort2*)(h + (size_t)s2 * D1 + ch);
        ushort2 v3 = *(const ushort2*)(h + (size_t)s3 * D1 + ch);
        ax0 += w0 * bf2f(v0.x); ay0 += w0 * bf2f(v0.y);
        ax1 += w1 * bf2f(v1.x); ay1 += w1 * bf2f(v1.y);
        ax2 += w2 * bf2f(v2.x); ay2 += w2 * bf2f(v2.y);
        ax3 += w3 * bf2f(v3.x); ay3 += w3 * bf2f(v3.y);
    }
    for (; k < end; k++) {
        int s0 = colidx[k];
        float w0 = w[k];
        ushort2 v0 = *(const ushort2*)(h + (size_t)s0 * D1 + ch);
        ax0 += w0 * bf2f(v0.x); ay0 += w0 * bf2f(v0.y);
    }
    float ax = (ax0 + ax1) + (ax2 + ax3);
    float ay = (ay0 + ay1) + (ay2 + ay3);

    float2 bv = *(const float2*)(bias + ch);
    float ox = elu1(ax + bv.x);
    float oy = elu1(ay + bv.y);
    ushort2 oh, ol;
    oh.x = f2bf(ox); ol.x = f2bf(ox - bf2f(oh.x));
    oh.y = f2bf(oy); ol.y = f2bf(oy - bf2f(oh.y));
    *(ushort2*)(out_hi + (size_t)d * D1 + ch) = oh;
    *(ushort2*)(out_lo + (size_t)d * D1 + ch) = ol;
}

// ---------------- GAT layer 2 aggregation (no pooled atomics) ----------------

__global__ __launch_bounds__(256) void agg2_kernel(const unsigned short* __restrict__ h,
                                                   const float* __restrict__ als,
                                                   const float* __restrict__ ald,
                                                   const int* __restrict__ row_ptr,
                                                   const int* __restrict__ colidx,
                                                   const float* __restrict__ bias,
                                                   float* __restrict__ out) {
    int d = blockIdx.x;
    int t = threadIdx.x;
    int lane = t & 63, wave = t >> 6;
    int start = row_ptr[d], end = row_ptr[d + 1];

    __shared__ float ald_l[H2];
    __shared__ float wred[4][H2];
    __shared__ float sm[H2], sinv[H2];
    __shared__ int   s_src[128];
    __shared__ float s_w[128 * H2];
    __shared__ float red[256];

    if (t < H2) ald_l[t] = ald[d * H2 + t];
    __syncthreads();

    float mx[H2] = {-1e30f, -1e30f};
    for (int e = start + t; e < end; e += 256) {
        int s = colidx[e];
        const float* as = als + s * H2;
#pragma unroll
        for (int hh = 0; hh < H2; hh++)
            mx[hh] = fmaxf(mx[hh], leaky(as[hh] + ald_l[hh]));
    }
#pragma unroll
    for (int hh = 0; hh < H2; hh++)
#pragma unroll
        for (int off = 32; off; off >>= 1)
            mx[hh] = fmaxf(mx[hh], __shfl_down(mx[hh], off));
    if (lane == 0) {
#pragma unroll
        for (int hh = 0; hh < H2; hh++) wred[wave][hh] = mx[hh];
    }
    __syncthreads();
    if (t < H2) sm[t] = fmaxf(fmaxf(wred[0][t], wred[1][t]), fmaxf(wred[2][t], wred[3][t]));
    __syncthreads();

    float dn[H2] = {0.f, 0.f};
    for (int e = start + t; e < end; e += 256) {
        int s = colidx[e];
        const float* as = als + s * H2;
#pragma unroll
        for (int hh = 0; hh < H2; hh++)
            dn[hh] += __expf(leaky(as[hh] + ald_l[hh]) - sm[hh]);
    }
#pragma unroll
    for (int hh = 0; hh < H2; hh++)
#pragma unroll
        for (int off = 32; off; off >>= 1)
            dn[hh] += __shfl_down(dn[hh], off);
    if (lane == 0) {
#pragma unroll
        for (int hh = 0; hh < H2; hh++) wred[wave][hh] = dn[hh];
    }
    __syncthreads();
    if (t < H2) sinv[t] = 1.f / (wred[0][t] + wred[1][t] + wred[2][t] + wred[3][t] + 1e-16f);
    __syncthreads();

    // pass 3: k-loop unrolled x4 with independent accumulators
    float a0 = 0.f, a1 = 0.f, a2 = 0.f, a3 = 0.f;
    int myh = t >> 7;
    for (int base = start; base < end; base += 128) {
        int ne = min(128, end - base);
        if (t < ne * 2) {
            int ei = t >> 1, hh = t & 1;
            int s = colidx[base + ei];
            if (hh == 0) s_src[ei] = s;
            float v = leaky(als[s * H2 + hh] + ald_l[hh]);
            s_w[(ei << 1) + hh] = __expf(v - sm[hh]) * sinv[hh];
        }
        __syncthreads();
        int k = 0;
        for (; k + 3 < ne; k += 4) {
            int s0 = s_src[k],     s1 = s_src[k + 1];
            int s2 = s_src[k + 2], s3 = s_src[k + 3];
            float w0 = s_w[(k << 1) + myh],       w1 = s_w[((k + 1) << 1) + myh];
            float w2 = s_w[((k + 2) << 1) + myh], w3 = s_w[((k + 3) << 1) + myh];
            unsigned short v0 = h[(size_t)s0 * D2 + t];
            unsigned short v1 = h[(size_t)s1 * D2 + t];
            unsigned short v2 = h[(size_t)s2 * D2 + t];
            unsigned short v3 = h[(size_t)s3 * D2 + t];
            a0 += w0 * bf2f(v0); a1 += w1 * bf2f(v1);
            a2 += w2 * bf2f(v2); a3 += w3 * bf2f(v3);
        }
        for (; k < ne; k++) {
            a0 += s_w[(k << 1) + myh] * bf2f(h[(size_t)s_src[k] * D2 + t]);
        }
        __syncthreads();
    }
    red[t] = (a0 + a1) + (a2 + a3);
    __syncthreads();
    if (t < 128) {
        float v = (red[t] + red[t + 128]) * 0.5f + bias[t];
        out[(size_t)d * OUT2 + t] = elu1(v);
    }
}

// ---------------- pooling: per-graph sum of h2out (batch is SORTED) ----------------

__global__ __launch_bounds__(256) void pool_kernel(const float* __restrict__ h2,
                                                   const int* __restrict__ batch,
                                                   float* __restrict__ pooled) {
    int c = threadIdx.x & 127;
    int half = threadIdx.x >> 7;
    int n0 = blockIdx.x * 256 + half;
    int nend = blockIdx.x * 256 + 256;
    float acc = 0.f;
    int curg = batch[n0];
    for (int n = n0; n < nend; n += 2) {
        int g = batch[n];
        if (g != curg) {
            atomicAdd(&pooled[curg * OUT2 + c], acc);
            acc = 0.f; curg = g;
        }
        acc += h2[(size_t)n * OUT2 + c];
    }
    atomicAdd(&pooled[curg * OUT2 + c], acc);
}

// ---------------- per-graph head: proj + LN + risk MLP ----------------

__global__ __launch_bounds__(256) void final_kernel(const float* __restrict__ pooled_sum,
                                                    const int* __restrict__ n_g_i,
                                                    const int* __restrict__ e_cnt,
                                                    const float* __restrict__ projW,
                                                    const float* __restrict__ projb,
                                                    const float* __restrict__ lng,
                                                    const float* __restrict__ lnb,
                                                    const float* __restrict__ rhW1,
                                                    const float* __restrict__ rhb1,
                                                    const float* __restrict__ rhW2,
                                                    const float* __restrict__ rhb2,
                                                    float* __restrict__ out_se,
                                                    float* __restrict__ out_risk) {
    int b = blockIdx.x;
    int t = threadIdx.x;
    __shared__ float pooled[OUT2];
    __shared__ float pe[768];
    __shared__ float red[256];
    __shared__ float hid[32];
    __shared__ float stat_mu, stat_inv;

    float ng = (float)n_g_i[b];
    if (t < OUT2) pooled[t] = pooled_sum[b * OUT2 + t] / fmaxf(ng, 1.0f);
    __syncthreads();

    for (int j = t; j < 768; j += 256) {
        const float* wr = projW + (size_t)j * OUT2;
        float s = projb[j];
        for (int c = 0; c < OUT2; c++) s += pooled[c] * wr[c];
        pe[j] = s;
    }
    __syncthreads();

    float ls = 0.f, lq = 0.f;
    for (int j = t; j < 768; j += 256) { float v = pe[j]; ls += v; lq += v * v; }
    red[t] = ls;
    __syncthreads();
    for (int off = 128; off; off >>= 1) { if (t < off) red[t] += red[t + off]; __syncthreads(); }
    float tot = red[0];
    __syncthreads();
    red[t] = lq;
    __syncthreads();
    for (int off = 128; off; off >>= 1) { if (t < off) red[t] += red[t + off]; __syncthreads(); }
    float totq = red[0];
    if (t == 0) {
        float mu = tot / 768.f;
        float var = totq / 768.f - mu * mu;
        stat_mu = mu;
        stat_inv = 1.f / sqrtf(var + 1e-5f);
    }
    __syncthreads();
    float mu = stat_mu, inv = stat_inv;
    for (int j = t; j < 768; j += 256)
        out_se[(size_t)b * 768 + j] = (pe[j] - mu) * inv * lng[j] + lnb[j];

    float s0 = (float)e_cnt[b] / (ng + 1e-6f);
    float s1 = logf(ng + 1.0f);
    if (t < 32) {
        const float* wr = rhW1 + t * (OUT2 + 2);
        float s = rhb1[t];
        for (int c = 0; c < OUT2; c++) s += pooled[c] * wr[c];
        s += s0 * wr[OUT2] + s1 * wr[OUT2 + 1];
        hid[t] = fmaxf(s, 0.f);
    }
    __syncthreads();
    if (t == 0) {
        float s = rhb2[0];
        for (int k = 0; k < 32; k++) s += hid[k] * rhW2[k];
        out_risk[b] = 1.f / (1.f + __expf(-s));
    }
}

// ---------------- launch ----------------

extern "C" void kernel_launch(void* const* d_in, const int* in_sizes, int n_in,
                              void* d_out, int out_size, void* d_ws, size_t ws_size,
                              hipStream_t stream) {
    const float* x     = (const float*)d_in[0];
    const int*   ei    = (const int*)  d_in[1];
    const int*   batch = (const int*)  d_in[2];
    const float* W1    = (const float*)d_in[3];
    const float* a_s1  = (const float*)d_in[4];
    const float* a_d1  = (const float*)d_in[5];
    const float* b1    = (const float*)d_in[6];
    const float* W2    = (const float*)d_in[7];
    const float* a_s2  = (const float*)d_in[8];
    const float* a_d2  = (const float*)d_in[9];
    const float* b2    = (const float*)d_in[10];
    const float* projW = (const float*)d_in[11];
    const float* projb = (const float*)d_in[12];
    const float* lng   = (const float*)d_in[13];
    const float* lnb   = (const float*)d_in[14];
    const float* rhW1  = (const float*)d_in[15];
    const float* rhb1  = (const float*)d_in[16];
    const float* rhW2  = (const float*)d_in[17];
    const float* rhb2  = (const float*)d_in[18];

    char* ws = (char*)d_ws;
    size_t off = 0;
    auto alloc = [&](size_t bytes) -> void* {
        void* p = ws + off;
        off += (bytes + 255) & ~(size_t)255;
        return p;
    };

    unsigned short* regionA = (unsigned short*)alloc((size_t)2 * NN * D1 * 2);
    unsigned short* x_hi = regionA;
    unsigned short* x_lo = regionA + (size_t)NN * IN_F;
    unsigned short* h1hi = regionA;
    unsigned short* h1lo = regionA + (size_t)NN * D1;

    unsigned short* h1bf = (unsigned short*)alloc((size_t)NN * D1 * 2);
    unsigned short* h2bf = (unsigned short*)alloc((size_t)NN * D2 * 2);
    unsigned short* W1hi = (unsigned short*)alloc((size_t)D1 * IN_F * 2);
    unsigned short* W2hi = (unsigned short*)alloc((size_t)D2 * D1 * 2);
    unsigned short* W2lo = (unsigned short*)alloc((size_t)D2 * D1 * 2);
    float* als1   = (float*)alloc((size_t)NN * H1 * 4);
    float* ald1   = (float*)alloc((size_t)NN * H1 * 4);
    float* wt1    = (float*)alloc((size_t)H1 * ET * 4);
    float* als2   = (float*)alloc((size_t)NN * H2 * 4);
    float* ald2   = (float*)alloc((size_t)NN * H2 * 4);
    int*   row_ptr= (int*)  alloc((size_t)(NN + 1) * 4);
    int*   colidx = (int*)  alloc((size_t)ET * 4);
    size_t zoff = off;
    int*   deg    = (int*)  alloc((size_t)NN * 4);
    int*   cursor = (int*)  alloc((size_t)NN * 4);
    int*   n_g    = (int*)  alloc((size_t)NB * 4);
    int*   e_cnt  = (int*)  alloc((size_t)NB * 4);
    float* pooled = (float*)alloc((size_t)NB * OUT2 * 4);
    size_t zbytes = off - zoff;

    float* out_se   = (float*)d_out;
    float* h2out    = out_se + NB * 768;
    float* out_risk = h2out + (size_t)NN * OUT2;

    hipMemsetAsync(ws + zoff, 0, zbytes, stream);

    hist_kernel<<<(EE + 255) / 256, 256, 0, stream>>>(ei, batch, deg, n_g, e_cnt);
    scan_kernel<<<1, 1024, 0, stream>>>(deg, row_ptr);
    scatter_kernel<<<(ET + 255) / 256, 256, 0, stream>>>(ei, row_ptr, cursor, colidx);

    split_kernel<<<((NN * IN_F / 4) + 255) / 256, 256, 0, stream>>>(x, x_hi, x_lo, NN * IN_F / 4);
    tobf_kernel<<<((D1 * IN_F / 4) + 255) / 256, 256, 0, stream>>>(W1, W1hi, D1 * IN_F / 4);
    split_kernel<<<((D2 * D1 / 4) + 255) / 256, 256, 0, stream>>>(W2, W2hi, W2lo, D2 * D1 / 4);

    gemm_mfma<2><<<(NN / BM) * (D1 / BN), 256, 0, stream>>>(x_hi, x_lo, W1hi, W1hi, h1bf, NN, D1, IN_F);
    al_kernel<H1, HID1><<<NN, H1 * 64, 0, stream>>>(h1bf, a_s1, a_d1, als1, ald1);
    wstats1_kernel<<<NN / 4, 256, 0, stream>>>(als1, ald1, row_ptr, colidx, wt1);
    agg1_kernel<<<(NN / 4) * 8, 256, 0, stream>>>(h1bf, wt1, row_ptr, colidx, b1, h1hi, h1lo);

    gemm_mfma<3><<<(NN / BM) * (D2 / BN), 256, 0, stream>>>(h1hi, h1lo, W2hi, W2lo, h2bf, NN, D2, D1);
    al_kernel<H2, OUT2><<<NN, H2 * 64, 0, stream>>>(h2bf, a_s2, a_d2, als2, ald2);
    agg2_kernel<<<NN, 256, 0, stream>>>(h2bf, als2, ald2, row_ptr, colidx, b2, h2out);

    pool_kernel<<<NN / 256, 256, 0, stream>>>(h2out, batch, pooled);

    final_kernel<<<NB, 256, 0, stream>>>(pooled, n_g, e_cnt, projW, projb, lng, lnb,
                                         rhW1, rhb1, rhW2, rhb2, out_se, out_risk);
}

// Round 12
// 508.701 us; speedup vs baseline: 1.0268x; 1.0132x over previous
//
#include <hip/hip_runtime.h>
#include <math.h>

#define NN    16384
#define EE    262144
#define ET    (EE + NN)      // edges + self loops
#define NB    8
#define IN_F  768
#define HID1  256
#define H1    4
#define D1    (H1*HID1)      // 1024
#define OUT2  128
#define H2    2
#define D2    (H2*OUT2)      // 256

typedef __attribute__((ext_vector_type(8))) short short8;
typedef __attribute__((ext_vector_type(4))) float f32x4;

__device__ __forceinline__ unsigned short f2bf(float v) {
    unsigned u = __float_as_uint(v);
    u = (u + 0x7FFFu + ((u >> 16) & 1u)) >> 16;
    return (unsigned short)u;
}
__device__ __forceinline__ float bf2f(unsigned short b) {
    return __uint_as_float((unsigned)b << 16);
}

// ---------------- CSR build ----------------

__global__ void hist_kernel(const int* __restrict__ ei, const int* __restrict__ batch,
                            int* __restrict__ deg, int* __restrict__ n_g, int* __restrict__ e_cnt) {
    __shared__ int le[NB], ln[NB];
    int tid = threadIdx.x;
    if (tid < NB) { le[tid] = 0; ln[tid] = 0; }
    __syncthreads();
    int t = blockIdx.x * blockDim.x + tid;
    if (t < EE) {
        int s = ei[t];
        int d = ei[EE + t];
        atomicAdd(&deg[d], 1);
        atomicAdd(&le[batch[s]], 1);
    }
    if (t < NN) {
        atomicAdd(&ln[batch[t]], 1);
    }
    __syncthreads();
    if (tid < NB) {
        if (le[tid]) atomicAdd(&e_cnt[tid], le[tid]);
        if (ln[tid]) atomicAdd(&n_g[tid], ln[tid]);
    }
}

__global__ __launch_bounds__(1024) void scan_kernel(const int* __restrict__ deg, int* __restrict__ row_ptr) {
    __shared__ int sums[1024];
    int t = threadIdx.x;
    int base = t * 16;
    int local[16];
    int acc = 0;
#pragma unroll
    for (int i = 0; i < 16; i++) { local[i] = acc; acc += deg[base + i] + 1; }  // +1 = self loop
    sums[t] = acc;
    __syncthreads();
    for (int off = 1; off < 1024; off <<= 1) {
        int v = (t >= off) ? sums[t - off] : 0;
        __syncthreads();
        sums[t] += v;
        __syncthreads();
    }
    int prev = (t == 0) ? 0 : sums[t - 1];
#pragma unroll
    for (int i = 0; i < 16; i++) row_ptr[base + i] = prev + local[i];
    if (t == 1023) row_ptr[NN] = sums[1023];
}

__global__ void scatter_kernel(const int* __restrict__ ei, const int* __restrict__ row_ptr,
                               int* __restrict__ cursor, int* __restrict__ colidx) {
    int t = blockIdx.x * blockDim.x + threadIdx.x;
    if (t >= ET) return;
    int s, d;
    if (t < EE) { s = ei[t]; d = ei[EE + t]; }
    else        { s = d = t - EE; }
    int pos = row_ptr[d] + atomicAdd(&cursor[d], 1);
    colidx[pos] = s;
}

// ---------------- fp32 -> bf16 splits ----------------

__global__ void split_kernel(const float* __restrict__ in, unsigned short* __restrict__ hi,
                             unsigned short* __restrict__ lo, int n4) {
    int i = blockIdx.x * blockDim.x + threadIdx.x;
    if (i >= n4) return;
    float4 v = ((const float4*)in)[i];
    ushort4 h, l;
    h.x = f2bf(v.x); l.x = f2bf(v.x - bf2f(h.x));
    h.y = f2bf(v.y); l.y = f2bf(v.y - bf2f(h.y));
    h.z = f2bf(v.z); l.z = f2bf(v.z - bf2f(h.z));
    h.w = f2bf(v.w); l.w = f2bf(v.w - bf2f(h.w));
    ((ushort4*)hi)[i] = h;
    ((ushort4*)lo)[i] = l;
}

__global__ void tobf_kernel(const float* __restrict__ in, unsigned short* __restrict__ hi, int n4) {
    int i = blockIdx.x * blockDim.x + threadIdx.x;
    if (i >= n4) return;
    float4 v = ((const float4*)in)[i];
    ushort4 h;
    h.x = f2bf(v.x); h.y = f2bf(v.y); h.z = f2bf(v.z); h.w = f2bf(v.w);
    ((ushort4*)hi)[i] = h;
}

// ---------------- bf16 split MFMA GEMM, bf16 output ----------------
// XOR-swizzled LDS (kills 8-way bank conflict) + XCD-aware block swizzle
// (A-stripe L2-resident). See R8 notes.

__device__ __forceinline__ void ld_lds16(const unsigned short* g, unsigned short* l) {
    __builtin_amdgcn_global_load_lds((__attribute__((address_space(1))) void*)g,
                                     (__attribute__((address_space(3))) void*)l, 16, 0, 0);
}

#define BM 128
#define BN 128
#define BK 32

template <int TERMS>
__global__ __launch_bounds__(256) void gemm_mfma(const unsigned short* __restrict__ Ahi,
                                                 const unsigned short* __restrict__ Alo,
                                                 const unsigned short* __restrict__ Bhi,
                                                 const unsigned short* __restrict__ Blo,
                                                 unsigned short* __restrict__ Cb,
                                                 int M, int N, int K) {
    __shared__ __align__(16) unsigned short sA[2][BM * BK];
    __shared__ __align__(16) unsigned short sB[2][BN * BK];
    int t = threadIdx.x;
    int lane = t & 63, wave = t >> 6;

    int NC = N / BN;
    int b = blockIdx.x;
    int xcd = b & 7;
    int idx = b >> 3;
    int c = idx % NC;
    int rg = idx / NC;
    int bm = (rg * 8 + xcd) * BM;
    int bn = c * BN;

    int wm = (wave & 1) * 64, wn = (wave >> 1) * 64;

    const unsigned short* gbase;
    unsigned short* lbase;
    if      (wave == 0) { gbase = Ahi + (size_t)bm * K; lbase = sA[0]; }
    else if (wave == 1) { gbase = Alo + (size_t)bm * K; lbase = sA[1]; }
    else if (wave == 2) { gbase = Bhi + (size_t)bn * K; lbase = sB[0]; }
    else                { gbase = (TERMS == 3 ? Blo : Bhi) + (size_t)bn * K; lbase = sB[1]; }
    bool do_stage = (wave < 3) || (TERMS == 3);
    int schunk = (lane & 3) ^ ((lane >> 3) & 3);
    const unsigned short* gsrc = gbase + (size_t)(lane >> 2) * K + schunk * 8;

    f32x4 zero = {0.f, 0.f, 0.f, 0.f};
    f32x4 acc[4][4];
#pragma unroll
    for (int i = 0; i < 4; i++)
#pragma unroll
        for (int j = 0; j < 4; j++) acc[i][j] = zero;

    int row16 = lane & 15;
    int kq = ((lane >> 4) ^ ((row16 >> 1) & 3)) * 8;

    for (int k0 = 0; k0 < K; k0 += BK) {
        if (do_stage) {
#pragma unroll
            for (int i = 0; i < 8; i++)
                ld_lds16(gsrc + k0 + (size_t)(i * 16) * K, lbase + i * 16 * BK);
        }
        __syncthreads();

        short8 ah[4], alo[4], bh[4], blo[4];
#pragma unroll
        for (int mt = 0; mt < 4; mt++) {
            int r = (wm + mt * 16 + row16) * BK + kq;
            ah[mt]  = *(const short8*)&sA[0][r];
            alo[mt] = *(const short8*)&sA[1][r];
        }
#pragma unroll
        for (int nt = 0; nt < 4; nt++) {
            int r = (wn + nt * 16 + row16) * BK + kq;
            bh[nt]  = *(const short8*)&sB[0][r];
            if (TERMS == 3) blo[nt] = *(const short8*)&sB[1][r];
        }
#pragma unroll
        for (int mt = 0; mt < 4; mt++)
#pragma unroll
            for (int nt = 0; nt < 4; nt++) {
                acc[mt][nt] = __builtin_amdgcn_mfma_f32_16x16x32_bf16(ah[mt],  bh[nt],  acc[mt][nt], 0, 0, 0);
                acc[mt][nt] = __builtin_amdgcn_mfma_f32_16x16x32_bf16(alo[mt], bh[nt],  acc[mt][nt], 0, 0, 0);
                if (TERMS == 3)
                    acc[mt][nt] = __builtin_amdgcn_mfma_f32_16x16x32_bf16(ah[mt], blo[nt], acc[mt][nt], 0, 0, 0);
            }
        __syncthreads();
    }

    int crow0 = bm + wm + (lane >> 4) * 4;
    int ccol0 = bn + wn + row16;
#pragma unroll
    for (int mt = 0; mt < 4; mt++)
#pragma unroll
        for (int nt = 0; nt < 4; nt++)
#pragma unroll
            for (int reg = 0; reg < 4; reg++)
                Cb[(size_t)(crow0 + mt * 16 + reg) * N + ccol0 + nt * 16] = f2bf(acc[mt][nt][reg]);
}

// ---------------- attention logits ----------------

template <int H, int CH>
__global__ void al_kernel(const unsigned short* __restrict__ h, const float* __restrict__ a_s,
                          const float* __restrict__ a_d, float* __restrict__ als,
                          float* __restrict__ ald) {
    int node = blockIdx.x;
    int wave = threadIdx.x >> 6;
    int lane = threadIdx.x & 63;
    const unsigned short* row = h + (size_t)node * (H * CH) + wave * CH;
    float ss = 0.f, sd = 0.f;
#pragma unroll
    for (int c = lane; c < CH; c += 64) {
        float v = bf2f(row[c]);
        ss += v * a_s[wave * CH + c];
        sd += v * a_d[wave * CH + c];
    }
#pragma unroll
    for (int off = 32; off; off >>= 1) {
        ss += __shfl_down(ss, off);
        sd += __shfl_down(sd, off);
    }
    if (lane == 0) {
        als[node * H + wave] = ss;
        ald[node * H + wave] = sd;
    }
}

__device__ __forceinline__ float leaky(float v) { return v > 0.f ? v : 0.2f * v; }
__device__ __forceinline__ float elu1(float v) { return v > 0.f ? v : (__expf(v) - 1.f); }

// ---------------- per-edge softmax weights (layer 1): wave per node ----------------

__global__ __launch_bounds__(256) void wstats1_kernel(const float* __restrict__ als,
                                                      const float* __restrict__ ald,
                                                      const int* __restrict__ row_ptr,
                                                      const int* __restrict__ colidx,
                                                      float* __restrict__ wt) {
    int wave = threadIdx.x >> 6, lane = threadIdx.x & 63;
    int d = blockIdx.x * 4 + wave;
    int start = row_ptr[d], end = row_ptr[d + 1];
    float aldl[H1];
#pragma unroll
    for (int hh = 0; hh < H1; hh++) aldl[hh] = ald[d * H1 + hh];

    float mx[H1];
#pragma unroll
    for (int hh = 0; hh < H1; hh++) mx[hh] = -1e30f;
    for (int e = start + lane; e < end; e += 64) {
        int s = colidx[e];
        float4 as = *(const float4*)(als + s * H1);
        mx[0] = fmaxf(mx[0], leaky(as.x + aldl[0]));
        mx[1] = fmaxf(mx[1], leaky(as.y + aldl[1]));
        mx[2] = fmaxf(mx[2], leaky(as.z + aldl[2]));
        mx[3] = fmaxf(mx[3], leaky(as.w + aldl[3]));
    }
#pragma unroll
    for (int hh = 0; hh < H1; hh++)
#pragma unroll
        for (int off = 32; off; off >>= 1)
            mx[hh] = fmaxf(mx[hh], __shfl_xor(mx[hh], off));

    float dn[H1] = {0.f, 0.f, 0.f, 0.f};
    for (int e = start + lane; e < end; e += 64) {
        int s = colidx[e];
        float4 as = *(const float4*)(als + s * H1);
        dn[0] += __expf(leaky(as.x + aldl[0]) - mx[0]);
        dn[1] += __expf(leaky(as.y + aldl[1]) - mx[1]);
        dn[2] += __expf(leaky(as.z + aldl[2]) - mx[2]);
        dn[3] += __expf(leaky(as.w + aldl[3]) - mx[3]);
    }
#pragma unroll
    for (int hh = 0; hh < H1; hh++)
#pragma unroll
        for (int off = 32; off; off >>= 1)
            dn[hh] += __shfl_xor(dn[hh], off);
    float inv[H1];
#pragma unroll
    for (int hh = 0; hh < H1; hh++) inv[hh] = 1.f / (dn[hh] + 1e-16f);

    for (int e = start + lane; e < end; e += 64) {
        int s = colidx[e];
        float4 as = *(const float4*)(als + s * H1);
        wt[0 * (size_t)ET + e] = __expf(leaky(as.x + aldl[0]) - mx[0]) * inv[0];
        wt[1 * (size_t)ET + e] = __expf(leaky(as.y + aldl[1]) - mx[1]) * inv[1];
        wt[2 * (size_t)ET + e] = __expf(leaky(as.z + aldl[2]) - mx[2]) * inv[2];
        wt[3 * (size_t)ET + e] = __expf(leaky(as.w + aldl[3]) - mx[3]) * inv[3];
    }
}

// ---------------- GAT layer 1 aggregation: XCD channel-sliced, 2 edges/wave ----------------
// 8 slices of 128 ch; slice = blockIdx%8 binds slice->XCD (4.2MB slice, L2
// resident; FETCH 258->82MB). Half-wave e2=lane>>5 processes edge k+e2 with
// 4 ch/lane (ushort4): per-edge VALU halves vs R11's 2ch/lane (was VALUBusy
// 55%), trip count halves. Cross-half combine via shfl_xor(32). colidx/wt are
// padded +8 so the odd tail can read one-past-end (weight masked to 0).

__global__ __launch_bounds__(256) void agg1_kernel(const unsigned short* __restrict__ h,
                                                   const float* __restrict__ wt,
                                                   const int* __restrict__ row_ptr,
                                                   const int* __restrict__ colidx,
                                                   const float* __restrict__ bias,
                                                   unsigned short* __restrict__ out_hi,
                                                   unsigned short* __restrict__ out_lo) {
    int b = blockIdx.x;
    int slice = b & 7;
    int wave = threadIdx.x >> 6, lane = threadIdx.x & 63;
    int d = (b >> 3) * 4 + wave;
    int hd = slice >> 1;
    int e2 = lane >> 5;                    // which of 2 concurrent edges
    int ch = slice * 128 + (lane & 31) * 4;
    int start = row_ptr[d], end = row_ptr[d + 1];
    const float* w = wt + (size_t)hd * ET;
    const unsigned short* hc = h + ch;

    float4 a0 = make_float4(0.f, 0.f, 0.f, 0.f);
    float4 a1 = make_float4(0.f, 0.f, 0.f, 0.f);
    float4 a2 = make_float4(0.f, 0.f, 0.f, 0.f);
    float4 a3 = make_float4(0.f, 0.f, 0.f, 0.f);
    int k = start;
    for (; k + 7 < end; k += 8) {
        int e = k + e2;
        int s0 = colidx[e],     s1 = colidx[e + 2];
        int s2 = colidx[e + 4], s3 = colidx[e + 6];
        float w0 = w[e], w1 = w[e + 2], w2 = w[e + 4], w3 = w[e + 6];
        ushort4 v0 = *(const ushort4*)(hc + (size_t)s0 * D1);
        ushort4 v1 = *(const ushort4*)(hc + (size_t)s1 * D1);
        ushort4 v2 = *(const ushort4*)(hc + (size_t)s2 * D1);
        ushort4 v3 = *(const ushort4*)(hc + (size_t)s3 * D1);
        a0.x += w0 * bf2f(v0.x); a0.y += w0 * bf2f(v0.y);
        a0.z += w0 * bf2f(v0.z); a0.w += w0 * bf2f(v0.w);
        a1.x += w1 * bf2f(v1.x); a1.y += w1 * bf2f(v1.y);
        a1.z += w1 * bf2f(v1.z); a1.w += w1 * bf2f(v1.w);
        a2.x += w2 * bf2f(v2.x); a2.y += w2 * bf2f(v2.y);
        a2.z += w2 * bf2f(v2.z); a2.w += w2 * bf2f(v2.w);
        a3.x += w3 * bf2f(v3.x); a3.y += w3 * bf2f(v3.y);
        a3.z += w3 * bf2f(v3.z); a3.w += w3 * bf2f(v3.w);
    }
    for (; k < end; k += 2) {
        int e = k + e2;
        int s0 = colidx[e];                       // padded: e <= end is in-bounds
        float w0 = (e < end) ? w[e] : 0.f;
        ushort4 v0 = *(const ushort4*)(hc + (size_t)s0 * D1);
        a0.x += w0 * bf2f(v0.x); a0.y += w0 * bf2f(v0.y);
        a0.z += w0 * bf2f(v0.z); a0.w += w0 * bf2f(v0.w);
    }
    float4 acc;
    acc.x = (a0.x + a1.x) + (a2.x + a3.x);
    acc.y = (a0.y + a1.y) + (a2.y + a3.y);
    acc.z = (a0.z + a1.z) + (a2.z + a3.z);
    acc.w = (a0.w + a1.w) + (a2.w + a3.w);
    acc.x += __shfl_xor(acc.x, 32);
    acc.y += __shfl_xor(acc.y, 32);
    acc.z += __shfl_xor(acc.z, 32);
    acc.w += __shfl_xor(acc.w, 32);

    if (lane < 32) {
        float4 bv = *(const float4*)(bias + ch);
        float o0 = elu1(acc.x + bv.x);
        float o1 = elu1(acc.y + bv.y);
        float o2 = elu1(acc.z + bv.z);
        float o3 = elu1(acc.w + bv.w);
        ushort4 oh, ol;
        oh.x = f2bf(o0); ol.x = f2bf(o0 - bf2f(oh.x));
        oh.y = f2bf(o1); ol.y = f2bf(o1 - bf2f(oh.y));
        oh.z = f2bf(o2); ol.z = f2bf(o2 - bf2f(oh.z));
        oh.w = f2bf(o3); ol.w = f2bf(o3 - bf2f(oh.w));
        *(ushort4*)(out_hi + (size_t)d * D1 + ch) = oh;
        *(ushort4*)(out_lo + (size_t)d * D1 + ch) = ol;
    }
}

// ---------------- GAT layer 2 aggregation (no pooled atomics) ----------------

__global__ __launch_bounds__(256) void agg2_kernel(const unsigned short* __restrict__ h,
                                                   const float* __restrict__ als,
                                                   const float* __restrict__ ald,
                                                   const int* __restrict__ row_ptr,
                                                   const int* __restrict__ colidx,
                                                   const float* __restrict__ bias,
                                                   float* __restrict__ out) {
    int d = blockIdx.x;
    int t = threadIdx.x;
    int lane = t & 63, wave = t >> 6;
    int start = row_ptr[d], end = row_ptr[d + 1];

    __shared__ float ald_l[H2];
    __shared__ float wred[4][H2];
    __shared__ float sm[H2], sinv[H2];
    __shared__ int   s_src[128];
    __shared__ float s_w[128 * H2];
    __shared__ float red[256];

    if (t < H2) ald_l[t] = ald[d * H2 + t];
    __syncthreads();

    float mx[H2] = {-1e30f, -1e30f};
    for (int e = start + t; e < end; e += 256) {
        int s = colidx[e];
        const float* as = als + s * H2;
#pragma unroll
        for (int hh = 0; hh < H2; hh++)
            mx[hh] = fmaxf(mx[hh], leaky(as[hh] + ald_l[hh]));
    }
#pragma unroll
    for (int hh = 0; hh < H2; hh++)
#pragma unroll
        for (int off = 32; off; off >>= 1)
            mx[hh] = fmaxf(mx[hh], __shfl_down(mx[hh], off));
    if (lane == 0) {
#pragma unroll
        for (int hh = 0; hh < H2; hh++) wred[wave][hh] = mx[hh];
    }
    __syncthreads();
    if (t < H2) sm[t] = fmaxf(fmaxf(wred[0][t], wred[1][t]), fmaxf(wred[2][t], wred[3][t]));
    __syncthreads();

    float dn[H2] = {0.f, 0.f};
    for (int e = start + t; e < end; e += 256) {
        int s = colidx[e];
        const float* as = als + s * H2;
#pragma unroll
        for (int hh = 0; hh < H2; hh++)
            dn[hh] += __expf(leaky(as[hh] + ald_l[hh]) - sm[hh]);
    }
#pragma unroll
    for (int hh = 0; hh < H2; hh++)
#pragma unroll
        for (int off = 32; off; off >>= 1)
            dn[hh] += __shfl_down(dn[hh], off);
    if (lane == 0) {
#pragma unroll
        for (int hh = 0; hh < H2; hh++) wred[wave][hh] = dn[hh];
    }
    __syncthreads();
    if (t < H2) sinv[t] = 1.f / (wred[0][t] + wred[1][t] + wred[2][t] + wred[3][t] + 1e-16f);
    __syncthreads();

    // pass 3: k-loop unrolled x4 with independent accumulators
    float a0 = 0.f, a1 = 0.f, a2 = 0.f, a3 = 0.f;
    int myh = t >> 7;
    for (int base = start; base < end; base += 128) {
        int ne = min(128, end - base);
        if (t < ne * 2) {
            int ei = t >> 1, hh = t & 1;
            int s = colidx[base + ei];
            if (hh == 0) s_src[ei] = s;
            float v = leaky(als[s * H2 + hh] + ald_l[hh]);
            s_w[(ei << 1) + hh] = __expf(v - sm[hh]) * sinv[hh];
        }
        __syncthreads();
        int k = 0;
        for (; k + 3 < ne; k += 4) {
            int s0 = s_src[k],     s1 = s_src[k + 1];
            int s2 = s_src[k + 2], s3 = s_src[k + 3];
            float w0 = s_w[(k << 1) + myh],       w1 = s_w[((k + 1) << 1) + myh];
            float w2 = s_w[((k + 2) << 1) + myh], w3 = s_w[((k + 3) << 1) + myh];
            unsigned short v0 = h[(size_t)s0 * D2 + t];
            unsigned short v1 = h[(size_t)s1 * D2 + t];
            unsigned short v2 = h[(size_t)s2 * D2 + t];
            unsigned short v3 = h[(size_t)s3 * D2 + t];
            a0 += w0 * bf2f(v0); a1 += w1 * bf2f(v1);
            a2 += w2 * bf2f(v2); a3 += w3 * bf2f(v3);
        }
        for (; k < ne; k++) {
            a0 += s_w[(k << 1) + myh] * bf2f(h[(size_t)s_src[k] * D2 + t]);
        }
        __syncthreads();
    }
    red[t] = (a0 + a1) + (a2 + a3);
    __syncthreads();
    if (t < 128) {
        float v = (red[t] + red[t + 128]) * 0.5f + bias[t];
        out[(size_t)d * OUT2 + t] = elu1(v);
    }
}

// ---------------- pooling: per-graph sum of h2out (batch is SORTED) ----------------

__global__ __launch_bounds__(256) void pool_kernel(const float* __restrict__ h2,
                                                   const int* __restrict__ batch,
                                                   float* __restrict__ pooled) {
    int c = threadIdx.x & 127;
    int half = threadIdx.x >> 7;
    int n0 = blockIdx.x * 256 + half;
    int nend = blockIdx.x * 256 + 256;
    float acc = 0.f;
    int curg = batch[n0];
    for (int n = n0; n < nend; n += 2) {
        int g = batch[n];
        if (g != curg) {
            atomicAdd(&pooled[curg * OUT2 + c], acc);
            acc = 0.f; curg = g;
        }
        acc += h2[(size_t)n * OUT2 + c];
    }
    atomicAdd(&pooled[curg * OUT2 + c], acc);
}

// ---------------- per-graph head: proj + LN + risk MLP ----------------

__global__ __launch_bounds__(256) void final_kernel(const float* __restrict__ pooled_sum,
                                                    const int* __restrict__ n_g_i,
                                                    const int* __restrict__ e_cnt,
                                                    const float* __restrict__ projW,
                                                    const float* __restrict__ projb,
                                                    const float* __restrict__ lng,
                                                    const float* __restrict__ lnb,
                                                    const float* __restrict__ rhW1,
                                                    const float* __restrict__ rhb1,
                                                    const float* __restrict__ rhW2,
                                                    const float* __restrict__ rhb2,
                                                    float* __restrict__ out_se,
                                                    float* __restrict__ out_risk) {
    int b = blockIdx.x;
    int t = threadIdx.x;
    __shared__ float pooled[OUT2];
    __shared__ float pe[768];
    __shared__ float red[256];
    __shared__ float hid[32];
    __shared__ float stat_mu, stat_inv;

    float ng = (float)n_g_i[b];
    if (t < OUT2) pooled[t] = pooled_sum[b * OUT2 + t] / fmaxf(ng, 1.0f);
    __syncthreads();

    for (int j = t; j < 768; j += 256) {
        const float* wr = projW + (size_t)j * OUT2;
        float s = projb[j];
        for (int c = 0; c < OUT2; c++) s += pooled[c] * wr[c];
        pe[j] = s;
    }
    __syncthreads();

    float ls = 0.f, lq = 0.f;
    for (int j = t; j < 768; j += 256) { float v = pe[j]; ls += v; lq += v * v; }
    red[t] = ls;
    __syncthreads();
    for (int off = 128; off; off >>= 1) { if (t < off) red[t] += red[t + off]; __syncthreads(); }
    float tot = red[0];
    __syncthreads();
    red[t] = lq;
    __syncthreads();
    for (int off = 128; off; off >>= 1) { if (t < off) red[t] += red[t + off]; __syncthreads(); }
    float totq = red[0];
    if (t == 0) {
        float mu = tot / 768.f;
        float var = totq / 768.f - mu * mu;
        stat_mu = mu;
        stat_inv = 1.f / sqrtf(var + 1e-5f);
    }
    __syncthreads();
    float mu = stat_mu, inv = stat_inv;
    for (int j = t; j < 768; j += 256)
        out_se[(size_t)b * 768 + j] = (pe[j] - mu) * inv * lng[j] + lnb[j];

    float s0 = (float)e_cnt[b] / (ng + 1e-6f);
    float s1 = logf(ng + 1.0f);
    if (t < 32) {
        const float* wr = rhW1 + t * (OUT2 + 2);
        float s = rhb1[t];
        for (int c = 0; c < OUT2; c++) s += pooled[c] * wr[c];
        s += s0 * wr[OUT2] + s1 * wr[OUT2 + 1];
        hid[t] = fmaxf(s, 0.f);
    }
    __syncthreads();
    if (t == 0) {
        float s = rhb2[0];
        for (int k = 0; k < 32; k++) s += hid[k] * rhW2[k];
        out_risk[b] = 1.f / (1.f + __expf(-s));
    }
}

// ---------------- launch ----------------

extern "C" void kernel_launch(void* const* d_in, const int* in_sizes, int n_in,
                              void* d_out, int out_size, void* d_ws, size_t ws_size,
                              hipStream_t stream) {
    const float* x     = (const float*)d_in[0];
    const int*   ei    = (const int*)  d_in[1];
    const int*   batch = (const int*)  d_in[2];
    const float* W1    = (const float*)d_in[3];
    const float* a_s1  = (const float*)d_in[4];
    const float* a_d1  = (const float*)d_in[5];
    const float* b1    = (const float*)d_in[6];
    const float* W2    = (const float*)d_in[7];
    const float* a_s2  = (const float*)d_in[8];
    const float* a_d2  = (const float*)d_in[9];
    const float* b2    = (const float*)d_in[10];
    const float* projW = (const float*)d_in[11];
    const float* projb = (const float*)d_in[12];
    const float* lng   = (const float*)d_in[13];
    const float* lnb   = (const float*)d_in[14];
    const float* rhW1  = (const float*)d_in[15];
    const float* rhb1  = (const float*)d_in[16];
    const float* rhW2  = (const float*)d_in[17];
    const float* rhb2  = (const float*)d_in[18];

    char* ws = (char*)d_ws;
    size_t off = 0;
    auto alloc = [&](size_t bytes) -> void* {
        void* p = ws + off;
        off += (bytes + 255) & ~(size_t)255;
        return p;
    };

    unsigned short* regionA = (unsigned short*)alloc((size_t)2 * NN * D1 * 2);
    unsigned short* x_hi = regionA;
    unsigned short* x_lo = regionA + (size_t)NN * IN_F;
    unsigned short* h1hi = regionA;
    unsigned short* h1lo = regionA + (size_t)NN * D1;

    unsigned short* h1bf = (unsigned short*)alloc((size_t)NN * D1 * 2);
    unsigned short* h2bf = (unsigned short*)alloc((size_t)NN * D2 * 2);
    unsigned short* W1hi = (unsigned short*)alloc((size_t)D1 * IN_F * 2);
    unsigned short* W2hi = (unsigned short*)alloc((size_t)D2 * D1 * 2);
    unsigned short* W2lo = (unsigned short*)alloc((size_t)D2 * D1 * 2);
    float* als1   = (float*)alloc((size_t)NN * H1 * 4);
    float* ald1   = (float*)alloc((size_t)NN * H1 * 4);
    float* wt1    = (float*)alloc(((size_t)H1 * ET + 8) * 4);   // +8 pad: agg1 tail reads e==end
    float* als2   = (float*)alloc((size_t)NN * H2 * 4);
    float* ald2   = (float*)alloc((size_t)NN * H2 * 4);
    int*   row_ptr= (int*)  alloc((size_t)(NN + 1) * 4);
    int*   colidx = (int*)  alloc(((size_t)ET + 8) * 4);        // +8 pad: agg1 tail reads e==end
    size_t zoff = off;
    int*   deg    = (int*)  alloc((size_t)NN * 4);
    int*   cursor = (int*)  alloc((size_t)NN * 4);
    int*   n_g    = (int*)  alloc((size_t)NB * 4);
    int*   e_cnt  = (int*)  alloc((size_t)NB * 4);
    float* pooled = (float*)alloc((size_t)NB * OUT2 * 4);
    size_t zbytes = off - zoff;

    float* out_se   = (float*)d_out;
    float* h2out    = out_se + NB * 768;
    float* out_risk = h2out + (size_t)NN * OUT2;

    hipMemsetAsync(ws + zoff, 0, zbytes, stream);
    hipMemsetAsync(colidx + ET, 0, 8 * 4, stream);   // pad region: valid node index 0

    hist_kernel<<<(EE + 255) / 256, 256, 0, stream>>>(ei, batch, deg, n_g, e_cnt);
    scan_kernel<<<1, 1024, 0, stream>>>(deg, row_ptr);
    scatter_kernel<<<(ET + 255) / 256, 256, 0, stream>>>(ei, row_ptr, cursor, colidx);

    split_kernel<<<((NN * IN_F / 4) + 255) / 256, 256, 0, stream>>>(x, x_hi, x_lo, NN * IN_F / 4);
    tobf_kernel<<<((D1 * IN_F / 4) + 255) / 256, 256, 0, stream>>>(W1, W1hi, D1 * IN_F / 4);
    split_kernel<<<((D2 * D1 / 4) + 255) / 256, 256, 0, stream>>>(W2, W2hi, W2lo, D2 * D1 / 4);

    gemm_mfma<2><<<(NN / BM) * (D1 / BN), 256, 0, stream>>>(x_hi, x_lo, W1hi, W1hi, h1bf, NN, D1, IN_F);
    al_kernel<H1, HID1><<<NN, H1 * 64, 0, stream>>>(h1bf, a_s1, a_d1, als1, ald1);
    wstats1_kernel<<<NN / 4, 256, 0, stream>>>(als1, ald1, row_ptr, colidx, wt1);
    agg1_kernel<<<(NN / 4) * 8, 256, 0, stream>>>(h1bf, wt1, row_ptr, colidx, b1, h1hi, h1lo);

    gemm_mfma<3><<<(NN / BM) * (D2 / BN), 256, 0, stream>>>(h1hi, h1lo, W2hi, W2lo, h2bf, NN, D2, D1);
    al_kernel<H2, OUT2><<<NN, H2 * 64, 0, stream>>>(h2bf, a_s2, a_d2, als2, ald2);
    agg2_kernel<<<NN, 256, 0, stream>>>(h2bf, als2, ald2, row_ptr, colidx, b2, h2out);

    pool_kernel<<<NN / 256, 256, 0, stream>>>(h2out, batch, pooled);

    final_kernel<<<NB, 256, 0, stream>>>(pooled, n_g, e_cnt, projW, projb, lng, lnb,
                                         rhW1, rhb1, rhW2, rhb2, out_se, out_risk);
}